// Round 4
// baseline (132.176 us; speedup 1.0000x reference)
//
#include <hip/hip_runtime.h>

#define B_N 8192
#define D_N 1024
#define C_N 1024
#define BM 128
#define BN 128
#define BK 64

typedef __attribute__((ext_vector_type(8))) __bf16 bf16x8;
typedef __attribute__((ext_vector_type(16))) float floatx16;

__device__ inline unsigned short f2bf(float f) {
  union { float f; unsigned int u; } cv; cv.f = f;
  unsigned int b = cv.u;
  unsigned int r = (b + 0x7FFFu + ((b >> 16) & 1u)) >> 16;  // RNE
  return (unsigned short)r;
}
__device__ inline float d4(const float4 a) {
  return a.x * a.x + a.y * a.y + a.z * a.z + a.w * a.w;
}
__device__ inline ushort4 pk4(const float4 v, const float s) {
  ushort4 u;
  u.x = f2bf(v.x * s); u.y = f2bf(v.y * s);
  u.z = f2bf(v.z * s); u.w = f2bf(v.w * s);
  return u;
}

// ---------------------------------------------------------------------------
// prep_a: blocks [0,2048): normalize emb_j -> z_j bf16 (1 row per wave).
//         blocks [2048,2056): build inverted label index idx[c*8+slot]=row.
// ---------------------------------------------------------------------------
__global__ __launch_bounds__(256) void prep_a(
    const float* __restrict__ emb_j, const int* __restrict__ labels,
    unsigned short* __restrict__ z_j, int* __restrict__ idx,
    float* __restrict__ out) {
  const int t = threadIdx.x;
  const int lane = t & 63;
  const int wid = t >> 6;
  const int b = blockIdx.x;

  if (b == 0 && t == 0) out[0] = 0.0f;

  if (b < 2048) {
    const int row = b * 4 + wid;
    const float4* src = (const float4*)(emb_j + (size_t)row * D_N);
    const float4 v0 = src[lane], v1 = src[lane + 64];
    const float4 v2 = src[lane + 128], v3 = src[lane + 192];
    float ss = d4(v0) + d4(v1) + d4(v2) + d4(v3);
    for (int o = 32; o; o >>= 1) ss += __shfl_xor(ss, o, 64);
    const float inv = 1.0f / fmaxf(sqrtf(ss), 1e-12f);
    ushort4* dst = (ushort4*)(z_j + (size_t)row * D_N);
    dst[lane] = pk4(v0, inv);
    dst[lane + 64] = pk4(v1, inv);
    dst[lane + 128] = pk4(v2, inv);
    dst[lane + 192] = pk4(v3, inv);
  } else {
    __shared__ int cnt[128];
    const int ib = b - 2048;
    for (int i = t; i < 128; i += 256) cnt[i] = 0;
    __syncthreads();
    const int4* lab4 = (const int4*)labels;
    for (int i = 0; i < 8; ++i) {
      const int qv = i * 256 + t;
      const int4 L = lab4[qv];
      const int base = qv * 4;
      if ((L.x >> 7) == ib) idx[L.x * 8 + atomicAdd(&cnt[L.x & 127], 1)] = base;
      if ((L.y >> 7) == ib) idx[L.y * 8 + atomicAdd(&cnt[L.y & 127], 1)] = base + 1;
      if ((L.z >> 7) == ib) idx[L.z * 8 + atomicAdd(&cnt[L.z & 127], 1)] = base + 2;
      if ((L.w >> 7) == ib) idx[L.w * 8 + atomicAdd(&cnt[L.w & 127], 1)] = base + 3;
    }
  }
}

// ---------------------------------------------------------------------------
// prep_b: one block per class c. Gather 8 emb_i rows from idx, normalize,
// average, write proto row (bf16) and p2[c].
// ---------------------------------------------------------------------------
__global__ __launch_bounds__(256) void prep_b(
    const float* __restrict__ emb_i, const int* __restrict__ idx,
    unsigned short* __restrict__ proto, float* __restrict__ p2) {
  __shared__ float sx[4][8];
  const int t = threadIdx.x;
  const int lane = t & 63;
  const int wid = t >> 6;
  const int c = blockIdx.x;

  int li[8];
#pragma unroll
  for (int k = 0; k < 8; ++k) li[k] = idx[c * 8 + k];

  const float* base = emb_i + wid * 256;
  float4 v[8];
  float ss[8];
#pragma unroll
  for (int k = 0; k < 8; ++k) {
    v[k] = ((const float4*)(base + (size_t)li[k] * D_N))[lane];
    ss[k] = d4(v[k]);
  }
#pragma unroll
  for (int k = 0; k < 8; ++k)
    for (int o = 32; o; o >>= 1) ss[k] += __shfl_xor(ss[k], o, 64);
  if (lane == 0) {
#pragma unroll
    for (int k = 0; k < 8; ++k) sx[wid][k] = ss[k];
  }
  __syncthreads();

  float4 a = make_float4(0.f, 0.f, 0.f, 0.f);
#pragma unroll
  for (int k = 0; k < 8; ++k) {
    const float tot = sx[0][k] + sx[1][k] + sx[2][k] + sx[3][k];
    const float iv = 1.0f / fmaxf(sqrtf(tot), 1e-12f);
    a.x += v[k].x * iv; a.y += v[k].y * iv;
    a.z += v[k].z * iv; a.w += v[k].w * iv;
  }
  a.x *= 0.125f; a.y *= 0.125f; a.z *= 0.125f; a.w *= 0.125f;

  float pp = d4(a);
  for (int o = 32; o; o >>= 1) pp += __shfl_xor(pp, o, 64);
  __syncthreads();
  if (lane == 0) sx[wid][0] = pp;
  __syncthreads();
  if (t == 0) p2[c] = sx[0][0] + sx[1][0] + sx[2][0] + sx[3][0];

  ((ushort4*)(proto + (size_t)c * D_N + wid * 256))[lane] = pk4(a, 1.0f);
}

// ---------------------------------------------------------------------------
// gemm_loss_kernel v7: 128x128 tile, BK=64, 256 thr (4 waves 2Mx2N, each
// 64x64 = 2x2 of 32x32x16). 2-deep LDS (2 x 32KB = 64KB) => 2 blocks/CU:
// two INDEPENDENT blocks per CU fill each other's vmcnt/barrier stalls
// (m114 cross-block overlap) -- the combination (counted prefetch + >=2
// blocks/CU) not tested in R0-R2. Grid 64x8 = 512 blocks.
//
// Per-iter: STAGE(kt+1 -> buf^1); vmcnt(8) [kt landed, kt+1 in flight];
// barrier; compute(buf); barrier. Tail peels vmcnt(0).
// WAR: buf^1 last read in compute(kt-1), protected by its trailing barrier
//      (stage issues only after this wave passed it; all waves did too).
// RAW: per-wave vmcnt(8) + pre-compute barrier (each wave waits its own
//      loads; barrier makes it collective).
// Fast-math BCE epilogue (verified R3). C/D layout (m74/m101):
// col=lane&31, row=(reg&3)+8*(reg>>2)+4*(lane>>5).
// ---------------------------------------------------------------------------
#define GLOAD(gp, lp)                                                        \
  __builtin_amdgcn_global_load_lds(                                          \
      (const __attribute__((address_space(1))) void*)(gp),                   \
      (__attribute__((address_space(3))) void*)(lp), 16, 0, 0)

__global__ __launch_bounds__(256) void gemm_loss_kernel(
    const unsigned short* __restrict__ Zj,   // [B,D] bf16
    const unsigned short* __restrict__ P,    // [C,D] bf16
    const float* __restrict__ p2,            // [C]
    const int* __restrict__ labels,          // [B]
    float* __restrict__ out) {               // scalar (zeroed by prep_a)
  // buffer = A(128x64) 16KB + B(128x64) 16KB = 16384 ushorts; x2 = 64KB
  __shared__ __align__(16) unsigned short lds[2 * 16384];
  __shared__ float sred[4];

  const int t = threadIdx.x;
  const int lane = t & 63;
  const int wid = t >> 6;
  const int wm = (wid >> 1) * 64;   // 2 waves in M
  const int wn = (wid & 1) * 64;    // 2 waves in N
  const int bm = blockIdx.x;
  const int bn = blockIdx.y;

  floatx16 acc[2][2];
#pragma unroll
  for (int i = 0; i < 2; ++i)
#pragma unroll
    for (int j = 0; j < 2; ++j)
      for (int r = 0; r < 16; ++r) acc[i][j][r] = 0.f;

  // staging: pass = 256 thr x 16B = 4KB = 32 rows x 128B. thread t -> row
  // (t>>3) (+32/pass), chunk slot t&7, fetching global chunk (t&7)^(row&7).
  // rows advance by 32 => row&7 invariant across passes.
  const int srow = t >> 3;
  const int g = (t & 7) ^ (srow & 7);
  const unsigned short* Ag = Zj + (size_t)(bm * BM + srow) * D_N + g * 8;
  const unsigned short* Bg = P + (size_t)(bn * BN + srow) * D_N + g * 8;
  unsigned short* const Al0 = (unsigned short*)lds + t * 8;
  unsigned short* const Bl0 = (unsigned short*)lds + 8192 + t * 8;

  // ds_read row bases (ushort units), row stride BK=64
  const int ar0 = (wm + (lane & 31)) * BK;
  const int ar1 = ar0 + 32 * BK;
  const int br0 = 8192 + (wn + (lane & 31)) * BK;
  const int br1 = br0 + 32 * BK;
  const int h = lane >> 5;  // K-half selector
  const int q = lane & 7;   // row&7 for swizzle inverse

#define STAGE(bi, kt)                                                        \
  do {                                                                       \
    const int _bo = (bi) * 16384;                                            \
    const int _k0 = (kt) * BK;                                               \
    GLOAD(Ag + (size_t)0 * 32 * D_N + _k0, Al0 + _bo + 0 * 2048);            \
    GLOAD(Ag + (size_t)1 * 32 * D_N + _k0, Al0 + _bo + 1 * 2048);            \
    GLOAD(Ag + (size_t)2 * 32 * D_N + _k0, Al0 + _bo + 2 * 2048);            \
    GLOAD(Ag + (size_t)3 * 32 * D_N + _k0, Al0 + _bo + 3 * 2048);            \
    GLOAD(Bg + (size_t)0 * 32 * D_N + _k0, Bl0 + _bo + 0 * 2048);            \
    GLOAD(Bg + (size_t)1 * 32 * D_N + _k0, Bl0 + _bo + 1 * 2048);            \
    GLOAD(Bg + (size_t)2 * 32 * D_N + _k0, Bl0 + _bo + 2 * 2048);            \
    GLOAD(Bg + (size_t)3 * 32 * D_N + _k0, Bl0 + _bo + 3 * 2048);            \
  } while (0)

  // compute one K-tile from buffer bi: 4 kk-slices, 16 ds_read_b128 +
  // 16 MFMA; plain code so the compiler emits fine-grained lgkmcnt
  // pipelining across slices (m97 behavior).
#define COMPUTE(bi)                                                          \
  {                                                                          \
    const unsigned short* Lb = (const unsigned short*)lds + (bi) * 16384;    \
    _Pragma("unroll") for (int kk = 0; kk < 4; ++kk) {                       \
      const int swz = ((kk * 2 + h) ^ q) << 3;                               \
      bf16x8 a0 = *(const bf16x8*)(Lb + ar0 + swz);                          \
      bf16x8 a1 = *(const bf16x8*)(Lb + ar1 + swz);                          \
      bf16x8 b0 = *(const bf16x8*)(Lb + br0 + swz);                          \
      bf16x8 b1 = *(const bf16x8*)(Lb + br1 + swz);                          \
      acc[0][0] = __builtin_amdgcn_mfma_f32_32x32x16_bf16(a0, b0, acc[0][0], 0, 0, 0); \
      acc[0][1] = __builtin_amdgcn_mfma_f32_32x32x16_bf16(a0, b1, acc[0][1], 0, 0, 0); \
      acc[1][0] = __builtin_amdgcn_mfma_f32_32x32x16_bf16(a1, b0, acc[1][0], 0, 0, 0); \
      acc[1][1] = __builtin_amdgcn_mfma_f32_32x32x16_bf16(a1, b1, acc[1][1], 0, 0, 0); \
    }                                                                        \
  }

  // prologue: stage K-tile 0 into buf 0 -> 8 outstanding
  STAGE(0, 0);

  int cur = 0;
  for (int kt = 0; kt < 15; ++kt) {
    STAGE(cur ^ 1, kt + 1);                       // -> 16 outstanding
    asm volatile("s_waitcnt vmcnt(8)" ::: "memory");  // kt landed
    __builtin_amdgcn_s_barrier();
    COMPUTE(cur);
    __builtin_amdgcn_s_barrier();                 // protects buf^1 overwrite
    cur ^= 1;
  }
  asm volatile("s_waitcnt vmcnt(0)" ::: "memory");
  __builtin_amdgcn_s_barrier();
  COMPUTE(cur);

  // epilogue: C/D layout col=lane&31, row=(reg&3)+8*(reg>>2)+4*(lane>>5)
  const int colbase = bn * BN + wn + (lane & 31);
  float lsum = 0.f;
#pragma unroll
  for (int mb = 0; mb < 2; ++mb) {
    const int rowbase = bm * BM + wm + mb * 32 + 4 * h;
    int labv[16];
#pragma unroll
    for (int reg = 0; reg < 16; ++reg)
      labv[reg] = labels[rowbase + (reg & 3) + 8 * (reg >> 2)];
#pragma unroll
    for (int nb2 = 0; nb2 < 2; ++nb2) {
      const int col = colbase + nb2 * 32;
      const float p2c = p2[col];
#pragma unroll
      for (int reg = 0; reg < 16; ++reg) {
        const float dot = acc[mb][nb2][reg];
        const float d2 = 1.0f + p2c - 2.0f * dot;
        const float s = 2.0f - sqrtf(fmaxf(d2, 0.0f));
        const float e = __expf(-fabsf(s));
        lsum += fmaxf(s, 0.0f) + __logf(1.0f + e) - ((labv[reg] == col) ? s : 0.0f);
      }
    }
  }
  for (int o = 32; o; o >>= 1) lsum += __shfl_xor(lsum, o, 64);
  if (lane == 0) sred[wid] = lsum;
  __syncthreads();
  if (t == 0)
    atomicAdd(out, (sred[0] + sred[1] + sred[2] + sred[3]) *
                       (1.0f / ((float)B_N * (float)C_N)));
}

// ---------------------------------------------------------------------------
extern "C" void kernel_launch(void* const* d_in, const int* in_sizes, int n_in,
                              void* d_out, int out_size, void* d_ws, size_t ws_size,
                              hipStream_t stream) {
  const float* emb_i = (const float*)d_in[0];
  const float* emb_j = (const float*)d_in[1];
  const int* labels = (const int*)d_in[2];
  float* out = (float*)d_out;

  char* ws = (char*)d_ws;
  unsigned short* z_j = (unsigned short*)ws;                         // 16 MB
  unsigned short* proto = (unsigned short*)(ws + (size_t)16777216);  // 2 MB
  float* p2 = (float*)(ws + (size_t)18874368);                       // 4 KB
  int* idx = (int*)(ws + (size_t)18878464);                          // 32 KB

  prep_a<<<dim3(2056), 256, 0, stream>>>(emb_j, labels, z_j, idx, out);
  prep_b<<<dim3(C_N), 256, 0, stream>>>(emb_i, idx, proto, p2);
  gemm_loss_kernel<<<dim3(B_N / BM, C_N / BN), 256, 0, stream>>>(z_j, proto,
                                                                 p2, labels, out);
}

// Round 5
// 128.989 us; speedup vs baseline: 1.0247x; 1.0247x over previous
//
#include <hip/hip_runtime.h>

#define B_N 8192
#define D_N 1024
#define C_N 1024
#define BM 128
#define BN 128
#define BK 64

typedef __attribute__((ext_vector_type(8))) __bf16 bf16x8;
typedef __attribute__((ext_vector_type(16))) float floatx16;

__device__ inline unsigned short f2bf(float f) {
  union { float f; unsigned int u; } cv; cv.f = f;
  unsigned int b = cv.u;
  unsigned int r = (b + 0x7FFFu + ((b >> 16) & 1u)) >> 16;  // RNE
  return (unsigned short)r;
}
__device__ inline float d4(const float4 a) {
  return a.x * a.x + a.y * a.y + a.z * a.z + a.w * a.w;
}
__device__ inline ushort4 pk4(const float4 v, const float s) {
  ushort4 u;
  u.x = f2bf(v.x * s); u.y = f2bf(v.y * s);
  u.z = f2bf(v.z * s); u.w = f2bf(v.w * s);
  return u;
}

// ---------------------------------------------------------------------------
// prep_fused: ONE dispatch, two block flavors (no cross-block dependency):
//   blocks [0,2048):     normalize emb_j -> z_j bf16 (1 row per wave).
//   blocks [2048,3072):  class c = b-2048. Self-scan labels (32KB staged to
//                        LDS once), find the 8 member rows, gather/normalize/
//                        average emb_i rows -> proto row (bf16) + p2[c].
// Self-scan removes the idx round-trip that forced the prep_a->prep_b
// serialization (R0-verified pattern).
// ---------------------------------------------------------------------------
__global__ __launch_bounds__(256) void prep_fused(
    const float* __restrict__ emb_i, const float* __restrict__ emb_j,
    const int* __restrict__ labels,
    unsigned short* __restrict__ z_j, unsigned short* __restrict__ proto,
    float* __restrict__ p2, float* __restrict__ out) {
  __shared__ int slab[8192];   // 32 KB label stage (proto blocks only)
  __shared__ float sx[4][8];
  __shared__ int list[8];
  __shared__ int scnt;

  const int t = threadIdx.x;
  const int lane = t & 63;
  const int wid = t >> 6;
  const int b = blockIdx.x;

  if (b < 2048) {
    if (b == 0 && t == 0) out[0] = 0.0f;
    const int row = b * 4 + wid;
    const float4* src = (const float4*)(emb_j + (size_t)row * D_N);
    const float4 v0 = src[lane], v1 = src[lane + 64];
    const float4 v2 = src[lane + 128], v3 = src[lane + 192];
    float ss = d4(v0) + d4(v1) + d4(v2) + d4(v3);
    for (int o = 32; o; o >>= 1) ss += __shfl_xor(ss, o, 64);
    const float inv = 1.0f / fmaxf(sqrtf(ss), 1e-12f);
    ushort4* dst = (ushort4*)(z_j + (size_t)row * D_N);
    dst[lane] = pk4(v0, inv);
    dst[lane + 64] = pk4(v1, inv);
    dst[lane + 128] = pk4(v2, inv);
    dst[lane + 192] = pk4(v3, inv);
    return;
  }

  const int c = b - 2048;
  if (t == 0) scnt = 0;
  // stage labels to LDS (32 KB, L2-served) then scan for class c
  int4* s4 = (int4*)slab;
  const int4* lab4 = (const int4*)labels;
#pragma unroll
  for (int i = 0; i < 8; ++i) s4[i * 256 + t] = lab4[i * 256 + t];
  __syncthreads();
#pragma unroll
  for (int i = 0; i < 8; ++i) {
    const int qv = i * 256 + t;
    const int4 L = s4[qv];
    const int base = qv * 4;
    if (L.x == c) list[atomicAdd(&scnt, 1) & 7] = base;
    if (L.y == c) list[atomicAdd(&scnt, 1) & 7] = base + 1;
    if (L.z == c) list[atomicAdd(&scnt, 1) & 7] = base + 2;
    if (L.w == c) list[atomicAdd(&scnt, 1) & 7] = base + 3;
  }
  __syncthreads();

  const float* base = emb_i + wid * 256;
  float4 v[8];
  float ss[8];
#pragma unroll
  for (int k = 0; k < 8; ++k) {
    v[k] = ((const float4*)(base + (size_t)list[k] * D_N))[lane];
    ss[k] = d4(v[k]);
  }
#pragma unroll
  for (int k = 0; k < 8; ++k)
    for (int o = 32; o; o >>= 1) ss[k] += __shfl_xor(ss[k], o, 64);
  if (lane == 0) {
#pragma unroll
    for (int k = 0; k < 8; ++k) sx[wid][k] = ss[k];
  }
  __syncthreads();

  float4 a = make_float4(0.f, 0.f, 0.f, 0.f);
#pragma unroll
  for (int k = 0; k < 8; ++k) {
    const float tot = sx[0][k] + sx[1][k] + sx[2][k] + sx[3][k];
    const float iv = 1.0f / fmaxf(sqrtf(tot), 1e-12f);
    a.x += v[k].x * iv; a.y += v[k].y * iv;
    a.z += v[k].z * iv; a.w += v[k].w * iv;
  }
  a.x *= 0.125f; a.y *= 0.125f; a.z *= 0.125f; a.w *= 0.125f;

  float pp = d4(a);
  for (int o = 32; o; o >>= 1) pp += __shfl_xor(pp, o, 64);
  __syncthreads();
  if (lane == 0) sx[wid][0] = pp;
  __syncthreads();
  if (t == 0) p2[c] = sx[0][0] + sx[1][0] + sx[2][0] + sx[3][0];

  ((ushort4*)(proto + (size_t)c * D_N + wid * 256))[lane] = pk4(a, 1.0f);
}

// ---------------------------------------------------------------------------
// gemm_loss_kernel v7 (byte-identical to R4): 128x128 tile, BK=64, 256 thr
// (4 waves 2Mx2N, each 64x64 = 2x2 of 32x32x16). 2-deep LDS => 2 blocks/CU.
// Per-iter: STAGE(kt+1 -> buf^1); vmcnt(8); barrier; compute(buf); barrier.
// Fast-math BCE epilogue. C/D layout (m74/m101):
// col=lane&31, row=(reg&3)+8*(reg>>2)+4*(lane>>5).
// ---------------------------------------------------------------------------
#define GLOAD(gp, lp)                                                        \
  __builtin_amdgcn_global_load_lds(                                          \
      (const __attribute__((address_space(1))) void*)(gp),                   \
      (__attribute__((address_space(3))) void*)(lp), 16, 0, 0)

__global__ __launch_bounds__(256) void gemm_loss_kernel(
    const unsigned short* __restrict__ Zj,   // [B,D] bf16
    const unsigned short* __restrict__ P,    // [C,D] bf16
    const float* __restrict__ p2,            // [C]
    const int* __restrict__ labels,          // [B]
    float* __restrict__ out) {               // scalar (zeroed by prep_fused)
  __shared__ __align__(16) unsigned short lds[2 * 16384];
  __shared__ float sred[4];

  const int t = threadIdx.x;
  const int lane = t & 63;
  const int wid = t >> 6;
  const int wm = (wid >> 1) * 64;
  const int wn = (wid & 1) * 64;
  const int bm = blockIdx.x;
  const int bn = blockIdx.y;

  floatx16 acc[2][2];
#pragma unroll
  for (int i = 0; i < 2; ++i)
#pragma unroll
    for (int j = 0; j < 2; ++j)
      for (int r = 0; r < 16; ++r) acc[i][j][r] = 0.f;

  const int srow = t >> 3;
  const int g = (t & 7) ^ (srow & 7);
  const unsigned short* Ag = Zj + (size_t)(bm * BM + srow) * D_N + g * 8;
  const unsigned short* Bg = P + (size_t)(bn * BN + srow) * D_N + g * 8;
  unsigned short* const Al0 = (unsigned short*)lds + t * 8;
  unsigned short* const Bl0 = (unsigned short*)lds + 8192 + t * 8;

  const int ar0 = (wm + (lane & 31)) * BK;
  const int ar1 = ar0 + 32 * BK;
  const int br0 = 8192 + (wn + (lane & 31)) * BK;
  const int br1 = br0 + 32 * BK;
  const int h = lane >> 5;
  const int q = lane & 7;

#define STAGE(bi, kt)                                                        \
  do {                                                                       \
    const int _bo = (bi) * 16384;                                            \
    const int _k0 = (kt) * BK;                                               \
    GLOAD(Ag + (size_t)0 * 32 * D_N + _k0, Al0 + _bo + 0 * 2048);            \
    GLOAD(Ag + (size_t)1 * 32 * D_N + _k0, Al0 + _bo + 1 * 2048);            \
    GLOAD(Ag + (size_t)2 * 32 * D_N + _k0, Al0 + _bo + 2 * 2048);            \
    GLOAD(Ag + (size_t)3 * 32 * D_N + _k0, Al0 + _bo + 3 * 2048);            \
    GLOAD(Bg + (size_t)0 * 32 * D_N + _k0, Bl0 + _bo + 0 * 2048);            \
    GLOAD(Bg + (size_t)1 * 32 * D_N + _k0, Bl0 + _bo + 1 * 2048);            \
    GLOAD(Bg + (size_t)2 * 32 * D_N + _k0, Bl0 + _bo + 2 * 2048);            \
    GLOAD(Bg + (size_t)3 * 32 * D_N + _k0, Bl0 + _bo + 3 * 2048);            \
  } while (0)

#define COMPUTE(bi)                                                          \
  {                                                                          \
    const unsigned short* Lb = (const unsigned short*)lds + (bi) * 16384;    \
    _Pragma("unroll") for (int kk = 0; kk < 4; ++kk) {                       \
      const int swz = ((kk * 2 + h) ^ q) << 3;                               \
      bf16x8 a0 = *(const bf16x8*)(Lb + ar0 + swz);                          \
      bf16x8 a1 = *(const bf16x8*)(Lb + ar1 + swz);                          \
      bf16x8 b0 = *(const bf16x8*)(Lb + br0 + swz);                          \
      bf16x8 b1 = *(const bf16x8*)(Lb + br1 + swz);                          \
      acc[0][0] = __builtin_amdgcn_mfma_f32_32x32x16_bf16(a0, b0, acc[0][0], 0, 0, 0); \
      acc[0][1] = __builtin_amdgcn_mfma_f32_32x32x16_bf16(a0, b1, acc[0][1], 0, 0, 0); \
      acc[1][0] = __builtin_amdgcn_mfma_f32_32x32x16_bf16(a1, b0, acc[1][0], 0, 0, 0); \
      acc[1][1] = __builtin_amdgcn_mfma_f32_32x32x16_bf16(a1, b1, acc[1][1], 0, 0, 0); \
    }                                                                        \
  }

  STAGE(0, 0);

  int cur = 0;
  for (int kt = 0; kt < 15; ++kt) {
    STAGE(cur ^ 1, kt + 1);
    asm volatile("s_waitcnt vmcnt(8)" ::: "memory");
    __builtin_amdgcn_s_barrier();
    COMPUTE(cur);
    __builtin_amdgcn_s_barrier();
    cur ^= 1;
  }
  asm volatile("s_waitcnt vmcnt(0)" ::: "memory");
  __builtin_amdgcn_s_barrier();
  COMPUTE(cur);

  const int colbase = bn * BN + wn + (lane & 31);
  float lsum = 0.f;
#pragma unroll
  for (int mb = 0; mb < 2; ++mb) {
    const int rowbase = bm * BM + wm + mb * 32 + 4 * h;
    int labv[16];
#pragma unroll
    for (int reg = 0; reg < 16; ++reg)
      labv[reg] = labels[rowbase + (reg & 3) + 8 * (reg >> 2)];
#pragma unroll
    for (int nb2 = 0; nb2 < 2; ++nb2) {
      const int col = colbase + nb2 * 32;
      const float p2c = p2[col];
#pragma unroll
      for (int reg = 0; reg < 16; ++reg) {
        const float dot = acc[mb][nb2][reg];
        const float d2 = 1.0f + p2c - 2.0f * dot;
        const float s = 2.0f - sqrtf(fmaxf(d2, 0.0f));
        const float e = __expf(-fabsf(s));
        lsum += fmaxf(s, 0.0f) + __logf(1.0f + e) - ((labv[reg] == col) ? s : 0.0f);
      }
    }
  }
  for (int o = 32; o; o >>= 1) lsum += __shfl_xor(lsum, o, 64);
  if (lane == 0) sred[wid] = lsum;
  __syncthreads();
  if (t == 0)
    atomicAdd(out, (sred[0] + sred[1] + sred[2] + sred[3]) *
                       (1.0f / ((float)B_N * (float)C_N)));
}

// ---------------------------------------------------------------------------
extern "C" void kernel_launch(void* const* d_in, const int* in_sizes, int n_in,
                              void* d_out, int out_size, void* d_ws, size_t ws_size,
                              hipStream_t stream) {
  const float* emb_i = (const float*)d_in[0];
  const float* emb_j = (const float*)d_in[1];
  const int* labels = (const int*)d_in[2];
  float* out = (float*)d_out;

  char* ws = (char*)d_ws;
  unsigned short* z_j = (unsigned short*)ws;                         // 16 MB
  unsigned short* proto = (unsigned short*)(ws + (size_t)16777216);  // 2 MB
  float* p2 = (float*)(ws + (size_t)18874368);                       // 4 KB

  prep_fused<<<dim3(3072), 256, 0, stream>>>(emb_i, emb_j, labels, z_j,
                                             proto, p2, out);
  gemm_loss_kernel<<<dim3(B_N / BM, C_N / BN), 256, 0, stream>>>(z_j, proto,
                                                                 p2, labels, out);
}